// Round 16
// baseline (112.405 us; speedup 1.0000x reference)
//
#include <hip/hip_runtime.h>

// Conv2d 3x3, cin=4, cout=4, pad=1, stride=1 on [4,4096,4096] fp32.
//
// Round-16: PERSISTENT 4-step blocks on the R14 skeleton (95.8 us).
// Grid 1024 = 8 x-strips x 128 y-bands; block sweeps 32 rows = 4 steps x
// 8 rows with the ci-pipeline running CONTINUOUSLY across steps: 16 phases
// (step,ci), one prologue + one drain per block instead of four. Phase p:
// stage(phase p+1) -> counted vmcnt -> barrier -> compute(p) -> [stores at
// ci==3] -> barrier. Stores join the vmcnt domain, so phases right after a
// store-phase wait vmcnt(21) (16 stores + 5 next chunks in flight; chunks
// retire first = exact), others vmcnt(5). LDS 2x10x512x4 = 40960 B exactly
// -> 4 blocks/CU, all resident. Thread = 4px x 4rows x 4cout (64 acc).

#define IW 4096
#define IH 4096
constexpr long long HWsz = (long long)IH * IW;

typedef float v4f __attribute__((ext_vector_type(4)));

__device__ __forceinline__ void gload_lds16(const float* g, float* l) {
    __builtin_amdgcn_global_load_lds(
        (const __attribute__((address_space(1))) char*)g,
        (__attribute__((address_space(3))) char*)l, 16, 0, 0);
}

// stage phase f = (step, ci): 10 rows x 2 half-strips = 20 chunks; wave w
// owns chunks 5w..5w+4 (5 DMAs, counted by vmcnt)
__device__ __forceinline__ void stage_phase(const float* __restrict__ xin,
                                            int f, float (*rbuf)[512],
                                            int ybase, int X0, int w, int l) {
    const int ci   = f & 3;
    const int y0   = ybase + (f >> 2) * 8;
    const float* plane = xin + (long long)ci * HWsz;
    #pragma unroll
    for (int k = 0; k < 5; ++k) {
        const int c = 5 * w + k;                 // chunk id (wave-uniform)
        const int r = c >> 1;                    // staged row 0..9
        const int h = c & 1;                     // half-strip
        int yy = y0 - 1 + r;
        int yc = yy < 0 ? 0 : (yy >= IH ? IH - 1 : yy);   // clamp: pad rows
        gload_lds16(plane + (long long)yc * IW + (X0 + 256 * h + 4 * l),
                    &rbuf[r][256 * h]);
    }
}

__device__ __forceinline__ void compute_ci(float acc[4][4][4],
                                           const float (*rbuf)[512],
                                           const float* __restrict__ xin,
                                           const float* __restrict__ wt,
                                           int ci, int y0, int X0,
                                           int p_u, int tx) {
    const float* plane = xin + (long long)ci * HWsz;
    #pragma unroll
    for (int dy = 0; dy < 6; ++dy) {
        const int r  = 4 * p_u + dy;             // staged row (wave-uniform)
        const int yy = y0 - 1 + r;               // global input row (uniform)
        if (yy >= 0 && yy < IH) {                // wave-uniform row skip
            // wave-uniform halo addresses -> scalar loads
            const float hL = (X0 > 0)
                ? plane[(long long)yy * IW + X0 - 1]   : 0.f;
            const float hR = (X0 + 512 < IW)
                ? plane[(long long)yy * IW + X0 + 512] : 0.f;
            const v4f a = *reinterpret_cast<const v4f*>(&rbuf[r][4 * tx]);
            const float L = (tx == 0)   ? hL : rbuf[r][4 * tx - 1];
            const float R = (tx == 127) ? hR : rbuf[r][4 * tx + 4];
            float vv[6] = {L, a.x, a.y, a.z, a.w, R};
            #pragma unroll
            for (int rk = 0; rk < 3; ++rk) {
                const int o = dy - rk;           // output row offset in pair
                if (o >= 0 && o < 4) {
                    #pragma unroll
                    for (int co = 0; co < 4; ++co) {
                        #pragma unroll
                        for (int kx = 0; kx < 3; ++kx) {
                            const float w = wt[((co * 4 + ci) * 3 + rk) * 3 + kx];
                            #pragma unroll
                            for (int p = 0; p < 4; ++p)
                                acc[o][co][p] = fmaf(w, vv[p + kx], acc[o][co][p]);
                        }
                    }
                }
            }
        }
    }
}

__global__ __launch_bounds__(256) void conv3x3_kernel(
    const float* __restrict__ xin,   // [4][4096][4096]
    const float* __restrict__ wt,    // [4][4][3][3]
    float* __restrict__ out)         // [4][4096][4096]
{
    __shared__ __align__(16) float rows[2][10][512];   // 40960 B exactly

    // grid 1024; bijective XCD swizzle: XCD x owns g in [x*128,(x+1)*128)
    // -> 16 consecutive 32-row bands (512-row slab) x all 8 strips
    const int bid   = blockIdx.x;
    const int g     = (bid & 7) * 128 + (bid >> 3);
    const int band  = g >> 3;                     // 0..127
    const int strip = g & 7;                      // 0..7
    const int ybase = band << 5;                  // 32 rows per block
    const int X0    = strip << 9;                 // 512-px strip
    const int t     = (int)threadIdx.x;
    const int w     = t >> 6, l = t & 63;
    const int tx    = t & 127;                    // px index within pair
    const int p_u   = __builtin_amdgcn_readfirstlane(t >> 7);  // pair 0/1

    float acc[4][4][4];                           // [orow][cout][px]
    #pragma unroll
    for (int o = 0; o < 4; ++o)
        #pragma unroll
        for (int co = 0; co < 4; ++co)
            #pragma unroll
            for (int p = 0; p < 4; ++p) acc[o][co][p] = 0.f;

    stage_phase(xin, 0, rows[0], ybase, X0, w, l);   // prologue: 5 DMAs/wave

    #pragma unroll 1
    for (int p = 0; p < 16; ++p) {
        const int cur = p & 1;
        if (p < 15) {
            stage_phase(xin, p + 1, rows[cur ^ 1], ybase, X0, w, l);
            if (p > 0 && (p & 3) == 0) {
                // phase after a store-phase: 16 stores + 5 new chunks live;
                // chunks of THIS phase retire before the stores (issue order)
                asm volatile("s_waitcnt vmcnt(21)\n\ts_barrier" ::: "memory");
            } else {
                asm volatile("s_waitcnt vmcnt(5)\n\ts_barrier" ::: "memory");
            }
        } else {
            asm volatile("s_waitcnt vmcnt(0)\n\ts_barrier" ::: "memory");
        }

        const int ci = p & 3;
        const int y0 = ybase + (p >> 2) * 8;
        compute_ci(acc, rows[cur], xin, wt, ci, y0, X0, p_u, tx);

        if (ci == 3) {                            // step complete: store+reset
            const int x0g = X0 + 4 * tx;
            #pragma unroll
            for (int o = 0; o < 4; ++o) {
                const long long obase =
                    (long long)(y0 + 4 * p_u + o) * IW + x0g;
                #pragma unroll
                for (int co = 0; co < 4; ++co) {
                    v4f ov;
                    ov.x = acc[o][co][0]; ov.y = acc[o][co][1];
                    ov.z = acc[o][co][2]; ov.w = acc[o][co][3];
                    __builtin_nontemporal_store(ov,
                        reinterpret_cast<v4f*>(out + co * HWsz + obase));
                    acc[o][co][0] = 0.f; acc[o][co][1] = 0.f;
                    acc[o][co][2] = 0.f; acc[o][co][3] = 0.f;
                }
            }
        }

        if (p < 15)
            asm volatile("s_barrier" ::: "memory");   // readers done before
                                                      // next stage overwrites
    }
}

extern "C" void kernel_launch(void* const* d_in, const int* in_sizes, int n_in,
                              void* d_out, int out_size, void* d_ws, size_t ws_size,
                              hipStream_t stream) {
    const float* xin = (const float*)d_in[0];
    const float* wt  = (const float*)d_in[1];
    float* out       = (float*)d_out;

    dim3 grid(1024), block(256);
    hipLaunchKernelGGL(conv3x3_kernel, grid, block, 0, stream, xin, wt, out);
}